// Round 2
// baseline (6013.725 us; speedup 1.0000x reference)
//
#include <hip/hip_runtime.h>

typedef __attribute__((ext_vector_type(8))) short short8;
typedef __attribute__((ext_vector_type(4))) float f32x4;

#define SEQ_BLOCKS 64

__device__ __forceinline__ unsigned short f2bf(float f) {
  unsigned u = __float_as_uint(f);
  u = u + 0x7fffu + ((u >> 16) & 1u);
  return (unsigned short)(u >> 16);
}
__device__ __forceinline__ float bf2f(unsigned short s) {
  return __uint_as_float(((unsigned)s) << 16);
}
__device__ __forceinline__ unsigned short f2h(float f) {
  _Float16 h = (_Float16)f;
  unsigned short r;
  __builtin_memcpy(&r, &h, 2);
  return r;
}
__device__ __forceinline__ float h2f(unsigned short u) {
  _Float16 h;
  __builtin_memcpy(&h, &u, 2);
  return (float)h;
}
__device__ __forceinline__ void gload16(const void* g, void* l) {
  __builtin_amdgcn_global_load_lds(
      (const __attribute__((address_space(1))) unsigned int*)g,
      (__attribute__((address_space(3))) unsigned int*)l, 16, 0, 0);
}
__device__ __forceinline__ float fast_sigmoid(float x) {
  return 1.0f / (1.0f + __expf(-x));
}
__device__ __forceinline__ float fast_tanh(float x) {
  return 2.0f / (1.0f + __expf(-2.0f * x)) - 1.0f;
}

// ---------- elementwise fp32 -> bf16 convert (vectorized) ----------
__global__ void k_conv_bf16(const float* __restrict__ in, unsigned short* __restrict__ out) {
  size_t i = ((size_t)blockIdx.x * 256 + threadIdx.x) * 4;
  float4 v = *(const float4*)(in + i);
  unsigned short o[4] = {f2bf(v.x), f2bf(v.y), f2bf(v.z), f2bf(v.w)};
  *(uint2*)(out + i) = *(const uint2*)o;
}

// ---------- transpose + convert: out[c][r] = bf16(in[r][c]) ----------
__global__ void k_transpose(const float* __restrict__ in, unsigned short* __restrict__ out,
                            int R, int C) {
  __shared__ float tile[32][33];
  int bx = blockIdx.x * 32, by = blockIdx.y * 32;
  int tx = threadIdx.x & 31, ty = threadIdx.x >> 5;  // ty 0..7
  for (int i = 0; i < 32; i += 8)
    tile[ty + i][tx] = in[(size_t)(by + ty + i) * C + bx + tx];
  __syncthreads();
  for (int i = 0; i < 32; i += 8)
    out[(size_t)(bx + ty + i) * R + by + tx] = f2bf(tile[tx][ty + i]);
}

// ---------- generic bf16 GEMM, C = A @ B^T (+bias), A[M][K], B[N][K] bf16 ----------
// OUTF16 = 0 -> store bf16 ; 1 -> store fp16
template<int OUTF16>
__global__ __launch_bounds__(256) void k_gemm_bt(
    const unsigned short* __restrict__ A, const unsigned short* __restrict__ B,
    unsigned short* __restrict__ C, const float* __restrict__ bias,
    int M, int N, int K) {
  __shared__ unsigned short As[128 * 32];
  __shared__ unsigned short Bs[128 * 32];
  const int tid = threadIdx.x;
  const int wv = tid >> 6, l = tid & 63;
  const int m0 = blockIdx.y * 128, n0 = blockIdx.x * 128;
  const int wr = (wv >> 1) * 64, wc = (wv & 1) * 64;
  f32x4 acc[4][4] = {};
  for (int k0 = 0; k0 < K; k0 += 32) {
#pragma unroll
    for (int j = 0; j < 2; ++j) {
      int c = wv * 128 + j * 64 + l;
      int row = c >> 2, kc = (c & 3) * 8;
      gload16(A + (size_t)(m0 + row) * K + k0 + kc, (char*)As + c * 16);
      gload16(B + (size_t)(n0 + row) * K + k0 + kc, (char*)Bs + c * 16);
    }
    __syncthreads();
    short8 af[4], bfr[4];
#pragma unroll
    for (int rf = 0; rf < 4; ++rf)
      af[rf] = *(const short8*)(As + (wr + rf * 16 + (l & 15)) * 32 + (l >> 4) * 8);
#pragma unroll
    for (int cf = 0; cf < 4; ++cf)
      bfr[cf] = *(const short8*)(Bs + (wc + cf * 16 + (l & 15)) * 32 + (l >> 4) * 8);
#pragma unroll
    for (int rf = 0; rf < 4; ++rf)
#pragma unroll
      for (int cf = 0; cf < 4; ++cf)
        acc[rf][cf] = __builtin_amdgcn_mfma_f32_16x16x32_bf16(af[rf], bfr[cf], acc[rf][cf], 0, 0, 0);
    __syncthreads();
  }
#pragma unroll
  for (int cf = 0; cf < 4; ++cf) {
    int col = n0 + wc + cf * 16 + (l & 15);
    float bv = bias ? bias[col] : 0.0f;
#pragma unroll
    for (int rf = 0; rf < 4; ++rf) {
#pragma unroll
      for (int i = 0; i < 4; ++i) {
        int row = m0 + wr + rf * 16 + (l >> 4) * 4 + i;
        float v = acc[rf][cf][i] + bv;
        C[(size_t)row * N + col] = OUTF16 ? f2h(v) : f2bf(v);
      }
    }
  }
}

// ---------- combined bias ----------
__global__ void k_bias(const float* __restrict__ Wxg, const float* __restrict__ bxg,
                       const float* __restrict__ b_in, const float* __restrict__ Whg,
                       const float* __restrict__ bhg, const float* __restrict__ b_hid,
                       float* __restrict__ gbias) {
  int col = blockIdx.x * 64 + (threadIdx.x >> 2);
  int p = threadIdx.x & 3;
  const float* wx = Wxg + (size_t)col * 1024;
  const float* wh = Whg + (size_t)col * 1024;
  float s = 0.f;
  for (int k = p * 256; k < p * 256 + 256; ++k)
    s += wx[k] * b_in[k] + wh[k] * b_hid[k];
  s += __shfl_down(s, 2, 4);
  s += __shfl_down(s, 1, 4);
  if (p == 0) gbias[col] = s + bxg[col] + bhg[col];
}

// ---------- persistent sequential LSTM scan ----------
// 64 blocks x 256 thr. Block owns j in [bid*16, bid*16+16); wave wv = gate wv.
// Sync protocol: per-block monotonic flag array (no central counter).
//  producer: plain h stores -> __syncthreads (drains vmcnt) -> ONE release
//            store flag[bid]=t+1 (single wbl2 per block per step).
//  consumer: all 4 waves poll all 64 flags with RELAXED loads (no L2 inv per
//            spin), then ONE acquire fence per wave (single buffer_inv), then
//            plain hbuf loads (L2-cached after first touch).
// GX for step t is prefetched into registers BEFORE the poll.
__global__ __launch_bounds__(256, 1) void k_lstm_seq(
    const unsigned short* __restrict__ GX,   // fp16 [16384][4096], bias folded
    const unsigned short* __restrict__ Whc,  // bf16 [4096][1024]
    const float* __restrict__ cell,          // [64][1024] f32
    unsigned short* __restrict__ hbuf,       // bf16 [2][64][1024]
    float* __restrict__ out,                 // h [64][1024], c [64][1024] f32
    unsigned* __restrict__ flags) {
  __shared__ unsigned short Wl[64 * 1024];   // 128 KB
  __shared__ float gbuf[64 * 68];            // padded stride 68
  const int tid = threadIdx.x;
  const int wv = tid >> 6, l = tid & 63;
  const int bid = blockIdx.x;

  // stage weight slice into LDS, XOR swizzle: byte = c*2048 + (kbyte ^ ((c&7)<<4))
  for (int c = wv; c < 64; c += 4) {
    const unsigned short* src = Whc + (size_t)((c >> 4) * 1024 + bid * 16 + (c & 15)) * 1024;
    int cx = (c & 7) << 4;
#pragma unroll
    for (int kk = 0; kk < 2; ++kk) {
      int chunk = l + kk * 64;  // 0..127 chunks of 16B
      short8 v = *(const short8*)(src + chunk * 8);
      *(short8*)((char*)Wl + c * 2048 + ((chunk * 16) ^ cx)) = v;
    }
  }
  const int jj = tid & 15;
  const int b0 = (tid >> 4) * 4;
  float c_reg[4];
#pragma unroll
  for (int i = 0; i < 4; ++i)
    c_reg[i] = cell[(size_t)(b0 + i) * 1024 + bid * 16 + jj];
  __syncthreads();

  const int cc = wv * 16 + (l & 15);         // block-local output col (gate wv)
  const int cxor = (cc & 7) << 4;
  const int gcol = wv * 1024 + bid * 16 + (l & 15);  // global gate col

  for (int t = 0; t < 256; ++t) {
    // --- prefetch x-path preactivation into registers (hidden under poll) ---
    unsigned short gxv[16];
#pragma unroll
    for (int rf = 0; rf < 4; ++rf)
#pragma unroll
      for (int i = 0; i < 4; ++i) {
        int b = rf * 16 + (l >> 4) * 4 + i;
        gxv[rf * 4 + i] = GX[(size_t)(t * 64 + b) * 4096 + gcol];
      }

    // --- wait for h(t) (all blocks flagged t); relaxed poll, one acquire ---
    if (t > 0) {
      const unsigned tgt = (unsigned)t;
      for (;;) {
        unsigned v = __hip_atomic_load(&flags[l], __ATOMIC_RELAXED, __HIP_MEMORY_SCOPE_AGENT);
        if (__all((int)(v >= tgt))) break;
      }
      __builtin_amdgcn_fence(__ATOMIC_ACQUIRE, "agent");
    }

    // --- h2h MFMA: acc[rf] = h(t) @ Whc_slice ---
    f32x4 acc[4] = {};
    const unsigned short* arow = hbuf + (t & 1) * 65536 + (l & 15) * 1024 + (l >> 4) * 8;
    for (int k0 = 0; k0 < 1024; k0 += 256) {
      short8 a[8][4], bb[8];
#pragma unroll
      for (int u = 0; u < 8; ++u) {
        int k = k0 + u * 32;
        bb[u] = *(const short8*)((const char*)Wl + cc * 2048 + (((l >> 4) * 16 + 2 * k) ^ cxor));
#pragma unroll
        for (int rf = 0; rf < 4; ++rf)
          a[u][rf] = *(const short8*)(arow + rf * 16 * 1024 + k);
      }
#pragma unroll
      for (int u = 0; u < 8; ++u)
#pragma unroll
        for (int rf = 0; rf < 4; ++rf)
          acc[rf] = __builtin_amdgcn_mfma_f32_16x16x32_bf16(a[u][rf], bb[u], acc[rf], 0, 0, 0);
    }

    // --- exchange gates via LDS (add x-path) ---
#pragma unroll
    for (int rf = 0; rf < 4; ++rf)
#pragma unroll
      for (int i = 0; i < 4; ++i)
        gbuf[(rf * 16 + (l >> 4) * 4 + i) * 68 + cc] = acc[rf][i] + h2f(gxv[rf * 4 + i]);
    __syncthreads();

    // --- elementwise update: thread owns (b0..b0+3, jj) ---
    float hnew[4];
#pragma unroll
    for (int i = 0; i < 4; ++i) {
      int b = b0 + i;
      float vi = gbuf[b * 68 + jj];
      float vf = gbuf[b * 68 + 16 + jj];
      float vg = gbuf[b * 68 + 32 + jj];
      float vo = gbuf[b * 68 + 48 + jj];
      float ig = fast_sigmoid(vi);
      float fg = fast_sigmoid(vf);
      float gg = fast_tanh(vg);
      float og = fast_sigmoid(vo);
      c_reg[i] = fg * c_reg[i] + ig * gg;
      hnew[i] = og * fast_tanh(c_reg[i]);
    }

    if (t == 255) {
#pragma unroll
      for (int i = 0; i < 4; ++i) {
        out[(size_t)(b0 + i) * 1024 + bid * 16 + jj] = hnew[i];
        out[65536 + (size_t)(b0 + i) * 1024 + bid * 16 + jj] = c_reg[i];
      }
    } else {
      // store h(t+1) into buffer (t+1)&1 (plain stores; release below flushes)
      unsigned short* hw = hbuf + ((t + 1) & 1) * 65536 + bid * 16 + jj;
#pragma unroll
      for (int i = 0; i < 4; ++i)
        hw[(size_t)(b0 + i) * 1024] = f2bf(hnew[i]);
      __syncthreads();  // drains each wave's vmcnt -> all stores in L2
      if (tid == 0)
        __hip_atomic_store(&flags[bid], (unsigned)(t + 1), __ATOMIC_RELEASE,
                           __HIP_MEMORY_SCOPE_AGENT);
    }
  }
}

extern "C" void kernel_launch(void* const* d_in, const int* in_sizes, int n_in,
                              void* d_out, int out_size, void* d_ws, size_t ws_size,
                              hipStream_t stream) {
  const float* x      = (const float*)d_in[0];
  const float* hidden = (const float*)d_in[1];
  const float* cell   = (const float*)d_in[2];
  const float* W_in   = (const float*)d_in[3];
  const float* b_in   = (const float*)d_in[4];
  const float* W_hid  = (const float*)d_in[5];
  const float* b_hid  = (const float*)d_in[6];
  const float* Wx_g   = (const float*)d_in[7];
  const float* bx_g   = (const float*)d_in[8];
  const float* Wh_g   = (const float*)d_in[9];
  const float* bh_g   = (const float*)d_in[10];
  float* out = (float*)d_out;

  char* ws = (char*)d_ws;
  unsigned short* GX    = (unsigned short*)(ws);                 // 134217728 B (fp16 [16384][4096])
  unsigned short* Xbf   = (unsigned short*)(ws + 134217728);     // 33554432
  unsigned short* WxGb  = (unsigned short*)(ws + 167772160);     // 8388608
  unsigned short* WhGb  = (unsigned short*)(ws + 176160768);     // 8388608
  unsigned short* WinT  = (unsigned short*)(ws + 184549376);     // 2097152
  unsigned short* WhidT = (unsigned short*)(ws + 186646528);     // 2097152
  unsigned short* Wxc   = (unsigned short*)(ws + 188743680);     // 8388608
  unsigned short* Whc   = (unsigned short*)(ws + 197132288);     // 8388608
  float*          gbias = (float*)(ws + 205520896);              // 16384
  unsigned short* hbuf  = (unsigned short*)(ws + 205537280);     // 262144
  unsigned*       flags = (unsigned*)(ws + 205799424);           // 256

  hipMemsetAsync(flags, 0, SEQ_BLOCKS * sizeof(unsigned), stream);
  // converts
  k_conv_bf16<<<16384, 256, 0, stream>>>(x, Xbf);
  k_conv_bf16<<<4096, 256, 0, stream>>>(Wx_g, WxGb);
  k_conv_bf16<<<4096, 256, 0, stream>>>(Wh_g, WhGb);
  k_transpose<<<dim3(32, 32), 256, 0, stream>>>(W_in, WinT, 1024, 1024);
  k_transpose<<<dim3(32, 32), 256, 0, stream>>>(W_hid, WhidT, 1024, 1024);
  // combined weights: Wxc = WxG @ W_in (via W_in^T), Whc = WhG @ W_hid
  k_gemm_bt<0><<<dim3(8, 32), 256, 0, stream>>>(WxGb, WinT, Wxc, nullptr, 4096, 1024, 1024);
  k_gemm_bt<0><<<dim3(8, 32), 256, 0, stream>>>(WhGb, WhidT, Whc, nullptr, 4096, 1024, 1024);
  k_bias<<<64, 256, 0, stream>>>(Wx_g, bx_g, b_in, Wh_g, bh_g, b_hid, gbias);
  // GX = X @ Wxc^T + gbias  (fp16 out)
  k_gemm_bt<1><<<dim3(32, 128), 256, 0, stream>>>(Xbf, Wxc, GX, gbias, 16384, 4096, 1024);
  // h0
  k_conv_bf16<<<64, 256, 0, stream>>>(hidden, hbuf);
  // sequential scan
  k_lstm_seq<<<SEQ_BLOCKS, 256, 0, stream>>>(GX, Whc, cell, hbuf, out, flags);
}

// Round 3
// 3302.060 us; speedup vs baseline: 1.8212x; 1.8212x over previous
//
#include <hip/hip_runtime.h>

typedef __attribute__((ext_vector_type(8))) short short8;
typedef __attribute__((ext_vector_type(4))) float f32x4;

#define SEQ_BLOCKS 64

__device__ __forceinline__ unsigned short f2bf(float f) {
  unsigned u = __float_as_uint(f);
  u = u + 0x7fffu + ((u >> 16) & 1u);
  return (unsigned short)(u >> 16);
}
__device__ __forceinline__ unsigned short f2h(float f) {
  _Float16 h = (_Float16)f;
  unsigned short r;
  __builtin_memcpy(&r, &h, 2);
  return r;
}
__device__ __forceinline__ float h2f(unsigned short u) {
  _Float16 h;
  __builtin_memcpy(&h, &u, 2);
  return (float)h;
}
__device__ __forceinline__ void gload16(const void* g, void* l) {
  __builtin_amdgcn_global_load_lds(
      (const __attribute__((address_space(1))) unsigned int*)g,
      (__attribute__((address_space(3))) unsigned int*)l, 16, 0, 0);
}
__device__ __forceinline__ float fast_sigmoid(float x) {
  return 1.0f / (1.0f + __expf(-x));
}
__device__ __forceinline__ float fast_tanh(float x) {
  return 2.0f / (1.0f + __expf(-2.0f * x)) - 1.0f;
}
// 16B load that bypasses L1/L2 (relaxed agent atomics -> sc0 sc1, no inv/wbl2)
__device__ __forceinline__ short8 load_h16(const unsigned short* p) {
  union { unsigned long long u[2]; short8 s; } r;
  r.u[0] = __hip_atomic_load((const unsigned long long*)p, __ATOMIC_RELAXED,
                             __HIP_MEMORY_SCOPE_AGENT);
  r.u[1] = __hip_atomic_load(((const unsigned long long*)p) + 1, __ATOMIC_RELAXED,
                             __HIP_MEMORY_SCOPE_AGENT);
  return r.s;
}

// ---------- elementwise fp32 -> bf16 convert (vectorized) ----------
__global__ void k_conv_bf16(const float* __restrict__ in, unsigned short* __restrict__ out) {
  size_t i = ((size_t)blockIdx.x * 256 + threadIdx.x) * 4;
  float4 v = *(const float4*)(in + i);
  unsigned short o[4] = {f2bf(v.x), f2bf(v.y), f2bf(v.z), f2bf(v.w)};
  *(uint2*)(out + i) = *(const uint2*)o;
}

// ---------- transpose + convert: out[c][r] = bf16(in[r][c]) ----------
__global__ void k_transpose(const float* __restrict__ in, unsigned short* __restrict__ out,
                            int R, int C) {
  __shared__ float tile[32][33];
  int bx = blockIdx.x * 32, by = blockIdx.y * 32;
  int tx = threadIdx.x & 31, ty = threadIdx.x >> 5;  // ty 0..7
  for (int i = 0; i < 32; i += 8)
    tile[ty + i][tx] = in[(size_t)(by + ty + i) * C + bx + tx];
  __syncthreads();
  for (int i = 0; i < 32; i += 8)
    out[(size_t)(bx + ty + i) * R + by + tx] = f2bf(tile[tx][ty + i]);
}

// ---------- generic bf16 GEMM, C = A @ B^T (+bias), A[M][K], B[N][K] bf16 ----------
template<int OUTF16>
__global__ __launch_bounds__(256) void k_gemm_bt(
    const unsigned short* __restrict__ A, const unsigned short* __restrict__ B,
    unsigned short* __restrict__ C, const float* __restrict__ bias,
    int M, int N, int K) {
  __shared__ unsigned short As[128 * 32];
  __shared__ unsigned short Bs[128 * 32];
  const int tid = threadIdx.x;
  const int wv = tid >> 6, l = tid & 63;
  const int m0 = blockIdx.y * 128, n0 = blockIdx.x * 128;
  const int wr = (wv >> 1) * 64, wc = (wv & 1) * 64;
  f32x4 acc[4][4] = {};
  for (int k0 = 0; k0 < K; k0 += 32) {
#pragma unroll
    for (int j = 0; j < 2; ++j) {
      int c = wv * 128 + j * 64 + l;
      int row = c >> 2, kc = (c & 3) * 8;
      gload16(A + (size_t)(m0 + row) * K + k0 + kc, (char*)As + c * 16);
      gload16(B + (size_t)(n0 + row) * K + k0 + kc, (char*)Bs + c * 16);
    }
    __syncthreads();
    short8 af[4], bfr[4];
#pragma unroll
    for (int rf = 0; rf < 4; ++rf)
      af[rf] = *(const short8*)(As + (wr + rf * 16 + (l & 15)) * 32 + (l >> 4) * 8);
#pragma unroll
    for (int cf = 0; cf < 4; ++cf)
      bfr[cf] = *(const short8*)(Bs + (wc + cf * 16 + (l & 15)) * 32 + (l >> 4) * 8);
#pragma unroll
    for (int rf = 0; rf < 4; ++rf)
#pragma unroll
      for (int cf = 0; cf < 4; ++cf)
        acc[rf][cf] = __builtin_amdgcn_mfma_f32_16x16x32_bf16(af[rf], bfr[cf], acc[rf][cf], 0, 0, 0);
    __syncthreads();
  }
#pragma unroll
  for (int cf = 0; cf < 4; ++cf) {
    int col = n0 + wc + cf * 16 + (l & 15);
    float bv = bias ? bias[col] : 0.0f;
#pragma unroll
    for (int rf = 0; rf < 4; ++rf) {
#pragma unroll
      for (int i = 0; i < 4; ++i) {
        int row = m0 + wr + rf * 16 + (l >> 4) * 4 + i;
        float v = acc[rf][cf][i] + bv;
        C[(size_t)row * N + col] = OUTF16 ? f2h(v) : f2bf(v);
      }
    }
  }
}

// ---------- combined bias ----------
__global__ void k_bias(const float* __restrict__ Wxg, const float* __restrict__ bxg,
                       const float* __restrict__ b_in, const float* __restrict__ Whg,
                       const float* __restrict__ bhg, const float* __restrict__ b_hid,
                       float* __restrict__ gbias) {
  int col = blockIdx.x * 64 + (threadIdx.x >> 2);
  int p = threadIdx.x & 3;
  const float* wx = Wxg + (size_t)col * 1024;
  const float* wh = Whg + (size_t)col * 1024;
  float s = 0.f;
  for (int k = p * 256; k < p * 256 + 256; ++k)
    s += wx[k] * b_in[k] + wh[k] * b_hid[k];
  s += __shfl_down(s, 2, 4);
  s += __shfl_down(s, 1, 4);
  if (p == 0) gbias[col] = s + bxg[col] + bhg[col];
}

// ---------- persistent sequential LSTM scan ----------
// 64 blocks x 256 thr. Block owns gate-cols [bid*16, bid*16+16) of each gate.
// Wave wv owns b-rows [wv*16, wv*16+16) x all 64 block gate-cols (A non-redundant).
// Cross-block h exchange through L3 ONLY: relaxed agent atomics (sc0 sc1,
// NO buffer_wbl2 / buffer_inv anywhere in the loop — the round1/2 killer).
// flags: one per block, padded to a 128B line each.
__global__ __launch_bounds__(256, 1) void k_lstm_seq(
    const unsigned short* __restrict__ GX,   // fp16 [16384][4096], bias folded
    const unsigned short* __restrict__ Whc,  // bf16 [4096][1024]
    const float* __restrict__ cell,          // [64][1024] f32
    unsigned short* __restrict__ hbuf,       // bf16 [2][64][1024]
    float* __restrict__ out,                 // h [64][1024], c [64][1024] f32
    unsigned* __restrict__ flags) {          // [64*32], stride 32
  __shared__ unsigned short Wl[64 * 1024];   // 128 KB, XOR-swizzled
  __shared__ float gbuf[64 * 68];            // [b][4*16 gate-cols], stride 68
  const int tid = threadIdx.x;
  const int wv = tid >> 6, l = tid & 63;
  const int bid = blockIdx.x;

  // stage weight slice into LDS, XOR swizzle: byte = c*2048 + (kbyte ^ ((c&7)<<4))
  for (int c = wv; c < 64; c += 4) {
    const unsigned short* src = Whc + (size_t)((c >> 4) * 1024 + bid * 16 + (c & 15)) * 1024;
    int cx = (c & 7) << 4;
#pragma unroll
    for (int kk = 0; kk < 2; ++kk) {
      int chunk = l + kk * 64;  // 0..127 chunks of 16B
      short8 v = *(const short8*)(src + chunk * 8);
      *(short8*)((char*)Wl + c * 2048 + ((chunk * 16) ^ cx)) = v;
    }
  }
  // elementwise ownership: row eb, 4 consecutive cols ej..ej+3
  const int eb = tid >> 2;
  const int ej = (tid & 3) * 4;
  float c_reg[4];
  {
    float4 c4 = *(const float4*)(cell + (size_t)eb * 1024 + bid * 16 + ej);
    c_reg[0] = c4.x; c_reg[1] = c4.y; c_reg[2] = c4.z; c_reg[3] = c4.w;
  }
  __syncthreads();

  const int cxor = ((l & 15) & 7) << 4;
  const int lrow = wv * 16 + (l & 15);       // A-row this lane feeds
  const int khalf = (l >> 4) * 8;            // k sub-offset within fragment

  for (int t = 0; t < 256; ++t) {
    // --- prefetch x-path preactivation (plain loads; complete during poll) ---
    unsigned short gxv[16];
#pragma unroll
    for (int cf = 0; cf < 4; ++cf)
#pragma unroll
      for (int i = 0; i < 4; ++i) {
        int b = wv * 16 + (l >> 4) * 4 + i;
        gxv[cf * 4 + i] = GX[(size_t)(t * 64 + b) * 4096 + cf * 1024 + bid * 16 + (l & 15)];
      }

    // --- wait for h(t): relaxed poll of per-block padded flags; no inv ---
    if (t > 0) {
      const unsigned tgt = (unsigned)t;
      for (;;) {
        unsigned v = __hip_atomic_load(&flags[l * 32], __ATOMIC_RELAXED,
                                       __HIP_MEMORY_SCOPE_AGENT);
        if (__all((int)(v >= tgt))) break;
      }
      __builtin_amdgcn_fence(__ATOMIC_ACQUIRE, "workgroup");
    }

    // --- load wave's A rows (16 x 1024 bf16) straight from L3, all up-front ---
    const unsigned short* hbase = hbuf + (t & 1) * 65536 + (size_t)lrow * 1024 + khalf;
    short8 a[32];
#pragma unroll
    for (int u = 0; u < 32; ++u) a[u] = load_h16(hbase + u * 32);

    // --- 128 MFMA: acc[cf] over all 64 gate-cols of this block ---
    f32x4 acc[4] = {};
#pragma unroll
    for (int u = 0; u < 32; ++u) {
#pragma unroll
      for (int cf = 0; cf < 4; ++cf) {
        short8 bb = *(const short8*)((const char*)Wl + (cf * 16 + (l & 15)) * 2048 +
                                     ((khalf * 2 + u * 64) ^ cxor));
        acc[cf] = __builtin_amdgcn_mfma_f32_16x16x32_bf16(a[u], bb, acc[cf], 0, 0, 0);
      }
    }

    // --- exchange gates via LDS (add x-path) ---
#pragma unroll
    for (int cf = 0; cf < 4; ++cf)
#pragma unroll
      for (int i = 0; i < 4; ++i)
        gbuf[(wv * 16 + (l >> 4) * 4 + i) * 68 + cf * 16 + (l & 15)] =
            acc[cf][i] + h2f(gxv[cf * 4 + i]);
    __syncthreads();

    // --- elementwise update: thread owns (eb, ej..ej+3) ---
    float hnew[4];
#pragma unroll
    for (int i = 0; i < 4; ++i) {
      float vi = gbuf[eb * 68 + ej + i];
      float vf = gbuf[eb * 68 + 16 + ej + i];
      float vg = gbuf[eb * 68 + 32 + ej + i];
      float vo = gbuf[eb * 68 + 48 + ej + i];
      float ig = fast_sigmoid(vi);
      float fg = fast_sigmoid(vf);
      float gg = fast_tanh(vg);
      float og = fast_sigmoid(vo);
      c_reg[i] = fg * c_reg[i] + ig * gg;
      hnew[i] = og * fast_tanh(c_reg[i]);
    }

    if (t == 255) {
      float4 h4 = {hnew[0], hnew[1], hnew[2], hnew[3]};
      float4 c4 = {c_reg[0], c_reg[1], c_reg[2], c_reg[3]};
      *(float4*)(out + (size_t)eb * 1024 + bid * 16 + ej) = h4;
      *(float4*)(out + 65536 + (size_t)eb * 1024 + bid * 16 + ej) = c4;
    } else {
      // write-through h(t+1) to L3 (packed u64, relaxed agent = sc0 sc1)
      unsigned short hs[4] = {f2bf(hnew[0]), f2bf(hnew[1]), f2bf(hnew[2]), f2bf(hnew[3])};
      unsigned long long hv;
      __builtin_memcpy(&hv, hs, 8);
      __hip_atomic_store(
          (unsigned long long*)(hbuf + ((t + 1) & 1) * 65536 + (size_t)eb * 1024 + bid * 16 + ej),
          hv, __ATOMIC_RELAXED, __HIP_MEMORY_SCOPE_AGENT);
      __syncthreads();  // drains all waves' vmcnt -> h stores complete at L3
      if (tid == 0)
        __hip_atomic_store(&flags[bid * 32], (unsigned)(t + 1), __ATOMIC_RELAXED,
                           __HIP_MEMORY_SCOPE_AGENT);
    }
  }
}

extern "C" void kernel_launch(void* const* d_in, const int* in_sizes, int n_in,
                              void* d_out, int out_size, void* d_ws, size_t ws_size,
                              hipStream_t stream) {
  const float* x      = (const float*)d_in[0];
  const float* hidden = (const float*)d_in[1];
  const float* cell   = (const float*)d_in[2];
  const float* W_in   = (const float*)d_in[3];
  const float* b_in   = (const float*)d_in[4];
  const float* W_hid  = (const float*)d_in[5];
  const float* b_hid  = (const float*)d_in[6];
  const float* Wx_g   = (const float*)d_in[7];
  const float* bx_g   = (const float*)d_in[8];
  const float* Wh_g   = (const float*)d_in[9];
  const float* bh_g   = (const float*)d_in[10];
  float* out = (float*)d_out;

  char* ws = (char*)d_ws;
  unsigned short* GX    = (unsigned short*)(ws);                 // 134217728 B (fp16 [16384][4096])
  unsigned short* Xbf   = (unsigned short*)(ws + 134217728);     // 33554432
  unsigned short* WxGb  = (unsigned short*)(ws + 167772160);     // 8388608
  unsigned short* WhGb  = (unsigned short*)(ws + 176160768);     // 8388608
  unsigned short* WinT  = (unsigned short*)(ws + 184549376);     // 2097152 (reused for flags after GEMMs)
  unsigned short* WhidT = (unsigned short*)(ws + 186646528);     // 2097152
  unsigned short* Wxc   = (unsigned short*)(ws + 188743680);     // 8388608
  unsigned short* Whc   = (unsigned short*)(ws + 197132288);     // 8388608
  float*          gbias = (float*)(ws + 205520896);              // 16384
  unsigned short* hbuf  = (unsigned short*)(ws + 205537280);     // 262144
  unsigned*       flags = (unsigned*)(ws + 184549376);           // 8192 (overlays WinT, freed by then)

  // converts
  k_conv_bf16<<<16384, 256, 0, stream>>>(x, Xbf);
  k_conv_bf16<<<4096, 256, 0, stream>>>(Wx_g, WxGb);
  k_conv_bf16<<<4096, 256, 0, stream>>>(Wh_g, WhGb);
  k_transpose<<<dim3(32, 32), 256, 0, stream>>>(W_in, WinT, 1024, 1024);
  k_transpose<<<dim3(32, 32), 256, 0, stream>>>(W_hid, WhidT, 1024, 1024);
  // combined weights: Wxc = WxG @ W_in (via W_in^T), Whc = WhG @ W_hid
  k_gemm_bt<0><<<dim3(8, 32), 256, 0, stream>>>(WxGb, WinT, Wxc, nullptr, 4096, 1024, 1024);
  k_gemm_bt<0><<<dim3(8, 32), 256, 0, stream>>>(WhGb, WhidT, Whc, nullptr, 4096, 1024, 1024);
  k_bias<<<64, 256, 0, stream>>>(Wx_g, bx_g, b_in, Wh_g, bh_g, b_hid, gbias);
  // GX = X @ Wxc^T + gbias  (fp16 out)
  k_gemm_bt<1><<<dim3(32, 128), 256, 0, stream>>>(Xbf, Wxc, GX, gbias, 16384, 4096, 1024);
  // h0
  k_conv_bf16<<<64, 256, 0, stream>>>(hidden, hbuf);
  // flags live where WinT was (all WinT consumers are done above)
  hipMemsetAsync(flags, 0, SEQ_BLOCKS * 32 * sizeof(unsigned), stream);
  // sequential scan
  k_lstm_seq<<<SEQ_BLOCKS, 256, 0, stream>>>(GX, Whc, cell, hbuf, out, flags);
}